// Round 1
// baseline (223.027 us; speedup 1.0000x reference)
//
#include <hip/hip_runtime.h>

// GCN 2-layer, N=100000, E=1600000, dim 64, fp32 in/out.
// Build: bucket_partition (512 thr, fixed-capacity bucket slabs, single-
// owner flush) -> bucket_csr (ONE block owns ONE bucket, 1024 thr, slab
// staged in LDS).  [R6 lesson: scatter windows must be single-block-owned.]
// Per layer: gemm_mfma (16x16x32 bf16 MFMA; rows pre-scaled by dinv[row]) +
// gather_nodes (R8: 1 node/WAVE, 8 edge-slots x 8 feature-chunks, dwordx4
// row loads -> 4x fewer VMEM instrs + 8x fewer srcs loads than the old
// 2-node/wave dword scheme; shfl_xor(8/16/32) reduce; layer-1 out bf16).
// Gather was MSHR/L2-random-service vs issue-bound ambiguity: this round
// tests the issue-bound hypothesis. bf16 rows are the byte floor given
// the 9.8e-3 absmax threshold.

#define BSHIFT 9             // bucket = dst >> 9  (512 nodes per bucket)
#define NPB 512              // nodes per bucket
#define NBUCK_MAX 256        // K = ceil(100000/512) = 196
#define CAP 10240            // slab capacity; E[edges/bucket]=8192, sd~90
#define CHUNK 4096

using frag16 = __attribute__((ext_vector_type(8))) short;   // 8 bf16
using fragf  = __attribute__((ext_vector_type(4))) float;   // 4 fp32 acc

__device__ __forceinline__ unsigned int f2bf(float f) {   // RNE fp32->bf16
    unsigned int u = __float_as_uint(f);
    return (u + 0x7fffu + ((u >> 16) & 1u)) >> 16;
}
__device__ __forceinline__ float bfl(unsigned int u) { return __uint_as_float(u << 16); }
__device__ __forceinline__ float bfh(unsigned int u) { return __uint_as_float(u & 0xffff0000u); }

// ---- partition edges into fixed-capacity bucket slabs (512 threads) ----
// pack = (src << 9) | (dst & 511)
__global__ __launch_bounds__(512) void bucket_partition(const int* __restrict__ src,
                                                        const int* __restrict__ dst,
                                                        int* __restrict__ bcur,
                                                        unsigned int* __restrict__ pairs,
                                                        int e) {
    __shared__ int cnt[NBUCK_MAX], offs[NBUCK_MAX], cur[NBUCK_MAX], base[NBUCK_MAX];
    __shared__ unsigned int sP[CHUNK];
    __shared__ unsigned char sB[CHUNK];
    const int t = threadIdx.x;
    const int cb = blockIdx.x * CHUNK;
    if (t < NBUCK_MAX) cnt[t] = 0;
    __syncthreads();

    // 8 edges/thread, int4 loads (cb is 16-aligned)
    unsigned int ep[8]; int eb[8];
#pragma unroll
    for (int j = 0; j < 2; j++) {
        int idx4 = (cb >> 2) + j * 512 + t;
        int idx  = idx4 << 2;
        if (idx + 3 < e) {
            int4 s4 = ((const int4*)src)[idx4];
            int4 d4 = ((const int4*)dst)[idx4];
            ep[j*4+0] = ((unsigned int)s4.x << BSHIFT) | (unsigned int)(d4.x & (NPB-1));
            ep[j*4+1] = ((unsigned int)s4.y << BSHIFT) | (unsigned int)(d4.y & (NPB-1));
            ep[j*4+2] = ((unsigned int)s4.z << BSHIFT) | (unsigned int)(d4.z & (NPB-1));
            ep[j*4+3] = ((unsigned int)s4.w << BSHIFT) | (unsigned int)(d4.w & (NPB-1));
            eb[j*4+0] = d4.x >> BSHIFT; eb[j*4+1] = d4.y >> BSHIFT;
            eb[j*4+2] = d4.z >> BSHIFT; eb[j*4+3] = d4.w >> BSHIFT;
#pragma unroll
            for (int q = 0; q < 4; q++) atomicAdd(&cnt[eb[j*4+q]], 1);
        } else {
#pragma unroll
            for (int q = 0; q < 4; q++) {
                int i = idx + q;
                eb[j*4+q] = -1;
                if (i < e) {
                    int s = src[i], d = dst[i];
                    ep[j*4+q] = ((unsigned int)s << BSHIFT) | (unsigned int)(d & (NPB-1));
                    eb[j*4+q] = d >> BSHIFT;
                    atomicAdd(&cnt[eb[j*4+q]], 1);
                }
            }
        }
    }
    __syncthreads();
    if (t < NBUCK_MAX) offs[t] = cnt[t];
    __syncthreads();
    for (int off = 1; off < NBUCK_MAX; off <<= 1) {
        int u = 0;
        if (t < NBUCK_MAX && t >= off) u = offs[t - off];
        __syncthreads();
        if (t < NBUCK_MAX) offs[t] += u;
        __syncthreads();
    }
    if (t < NBUCK_MAX) {
        int ex = offs[t] - cnt[t];
        offs[t] = ex;
        cur[t] = ex;
        if (cnt[t] > 0) base[t] = atomicAdd(&bcur[t], cnt[t]);
    }
    __syncthreads();
#pragma unroll
    for (int j = 0; j < 8; j++) {
        if (eb[j] >= 0) {
            int pos = atomicAdd(&cur[eb[j]], 1);
            sP[pos] = ep[j];
            sB[pos] = (unsigned char)eb[j];
        }
    }
    __syncthreads();
    int nv = min(CHUNK, e - cb);
    for (int i = t; i < nv; i += 512) {
        int b = sB[i];
        pairs[(size_t)b * CAP + base[b] + (i - offs[b])] = sP[i];
    }
}

// ---- per-bucket counting sort (slab in LDS, 1024 threads/block) ----
// Emits srcs (slab layout), meta = (beg,end,dinv) per node, dinv array.
__global__ __launch_bounds__(1024) void bucket_csr(const unsigned int* __restrict__ pairs,
                                                   const int* __restrict__ bcur,
                                                   float4* __restrict__ meta,
                                                   float* __restrict__ dinv,
                                                   int* __restrict__ srcs,
                                                   int n) {
    __shared__ unsigned int sP[CAP];
    __shared__ int cnt[NPB];
    __shared__ int cur[NPB];
    __shared__ int tsum[NPB];
    const int b = blockIdx.x;
    const int t = threadIdx.x;
    const int nb = b << BSHIFT;
    const int nn = min(NPB, n - nb);
    const size_t slab = (size_t)b * CAP;
    const int cE = bcur[b];

    const int c4 = cE >> 2;
    const uint4* p4 = (const uint4*)(pairs + slab);
    for (int i = t; i < c4; i += 1024) ((uint4*)sP)[i] = p4[i];
    for (int i = (c4 << 2) + t; i < cE; i += 1024) sP[i] = pairs[slab + i];
    if (t < NPB) cnt[t] = 0;
    __syncthreads();

    for (int i = t; i < cE; i += 1024)
        atomicAdd(&cnt[sP[i] & (NPB - 1)], 1);
    __syncthreads();

    int v = (t < NPB) ? cnt[t] : 0;
    if (t < NPB) tsum[t] = v;
    __syncthreads();
    for (int off = 1; off < NPB; off <<= 1) {
        int u = 0;
        if (t < NPB && t >= off) u = tsum[t - off];
        __syncthreads();
        if (t < NPB) tsum[t] += u;
        __syncthreads();
    }
    if (t < NPB) {
        int ex = tsum[t] - v;
        cur[t] = ex;
        if (t < nn) {
            int g = (int)slab + ex;
            float di = rsqrtf((float)v + 1.0f);
            meta[nb + t] = make_float4(__int_as_float(g), __int_as_float(g + v), di, 0.f);
            dinv[nb + t] = di;
        }
    }
    __syncthreads();
    for (int i = t; i < cE; i += 1024) {
        unsigned int p = sP[i];
        int pos = atomicAdd(&cur[p & (NPB - 1)], 1);
        srcs[slab + pos] = (int)(p >> BSHIFT);
    }
}

// ---- Y16[N,64](bf16) = (X @ W) * dinv[row], via 16x16x32 bf16 MFMA ----
// XF32: stage fp32 X -> bf16; else X is already bf16.
// LDS row stride 72 shorts (+8 pad): frag reads are 2-way conflict (free).
template<bool XF32>
__global__ __launch_bounds__(256) void gemm_mfma(const void* __restrict__ Xin,
                                                 const float* __restrict__ W,
                                                 const float* __restrict__ dinv,
                                                 unsigned short* __restrict__ Y16,
                                                 int nrows) {
    __shared__ __align__(16) short Xl[64 * 72];
    __shared__ __align__(16) short Wl[64 * 72];   // Wl[n][k] (transposed)
    __shared__ float dl[64];
    const int tid = threadIdx.x;
    const int rowBase = blockIdx.x * 64;

    for (int i = tid; i < 4096; i += 256) {
        int k = i >> 6, nn = i & 63;
        Wl[nn * 72 + k] = (short)f2bf(W[i]);
    }
    if (XF32) {
        const float* X = (const float*)Xin;
        for (int i = tid; i < 1024; i += 256) {
            int r = i >> 4, c4 = i & 15;
            int row = rowBase + r;
            float4 v = make_float4(0.f, 0.f, 0.f, 0.f);
            if (row < nrows) v = ((const float4*)(X + (size_t)row * 64))[c4];
            ushort4 pk = make_ushort4((unsigned short)f2bf(v.x), (unsigned short)f2bf(v.y),
                                      (unsigned short)f2bf(v.z), (unsigned short)f2bf(v.w));
            *(ushort4*)(Xl + r * 72 + c4 * 4) = pk;
        }
    } else {
        const unsigned short* X = (const unsigned short*)Xin;
        for (int i = tid; i < 512; i += 256) {
            int r = i >> 3, c8 = i & 7;
            int row = rowBase + r;
            uint4 v = make_uint4(0, 0, 0, 0);
            if (row < nrows) v = ((const uint4*)(X + (size_t)row * 64))[c8];
            *(uint4*)(Xl + r * 72 + c8 * 8) = v;
        }
    }
    if (tid < 64) {
        int row = rowBase + tid;
        dl[tid] = (row < nrows) ? dinv[row] : 0.f;
    }
    __syncthreads();

    const int w = tid >> 6;          // wave id -> 16-row stripe
    const int lane = tid & 63;
    const int q = lane >> 4, mn = lane & 15;

    fragf acc0 = {0,0,0,0}, acc1 = {0,0,0,0}, acc2 = {0,0,0,0}, acc3 = {0,0,0,0};
#pragma unroll
    for (int kk = 0; kk < 2; kk++) {
        frag16 a  = *(const frag16*)(Xl + (w * 16 + mn) * 72 + kk * 32 + q * 8);
        frag16 b0 = *(const frag16*)(Wl + ( 0 + mn) * 72 + kk * 32 + q * 8);
        frag16 b1 = *(const frag16*)(Wl + (16 + mn) * 72 + kk * 32 + q * 8);
        frag16 b2 = *(const frag16*)(Wl + (32 + mn) * 72 + kk * 32 + q * 8);
        frag16 b3 = *(const frag16*)(Wl + (48 + mn) * 72 + kk * 32 + q * 8);
        acc0 = __builtin_amdgcn_mfma_f32_16x16x32_bf16(a, b0, acc0, 0, 0, 0);
        acc1 = __builtin_amdgcn_mfma_f32_16x16x32_bf16(a, b1, acc1, 0, 0, 0);
        acc2 = __builtin_amdgcn_mfma_f32_16x16x32_bf16(a, b2, acc2, 0, 0, 0);
        acc3 = __builtin_amdgcn_mfma_f32_16x16x32_bf16(a, b3, acc3, 0, 0, 0);
    }
#pragma unroll
    for (int reg = 0; reg < 4; reg++) {
        int rl = w * 16 + q * 4 + reg;
        int row = rowBase + rl;
        if (row < nrows) {
            float di = dl[rl];
            size_t ro = (size_t)row * 64;
            Y16[ro +  0 + mn] = (unsigned short)f2bf(acc0[reg] * di);
            Y16[ro + 16 + mn] = (unsigned short)f2bf(acc1[reg] * di);
            Y16[ro + 32 + mn] = (unsigned short)f2bf(acc2[reg] * di);
            Y16[ro + 48 + mn] = (unsigned short)f2bf(acc3[reg] * di);
        }
    }
}

// ---- gather: 1 node/WAVE, 8 edge-slots (g) x 8 feature-chunks (c) ----
// Lane (g,c) loads dwordx4 = 8 bf16 features [8c,8c+8) of edge-slot g's
// source row; per-lane stride-8 walk over the node's CSR range; unroll-2
// keeps 16 lines in flight per wave.  shfl_xor(8/16/32) folds slots.
// Self-loop folded into g==0 acc init (rows pre-scaled by dinv[src]).
// OUT16: write bf16 (layer 1, feeds gemm_mfma<false>); else fp32 (output).
template<bool OUT16>
__global__ __launch_bounds__(256) void gather_nodes(const unsigned short* __restrict__ XW,
                                                    const float4* __restrict__ meta,
                                                    const int* __restrict__ srcs,
                                                    const float* __restrict__ bias,
                                                    void* __restrict__ outp, int n) {
    const int node = (blockIdx.x * 256 + threadIdx.x) >> 6;
    const int lane = threadIdx.x & 63;
    const int g = lane >> 3;          // edge slot 0..7
    const int c = lane & 7;           // feature chunk: features [8c, 8c+8)
    if (node >= n) return;
    const uint4* Xp4 = (const uint4*)XW;   // [N][8] chunks of 8 bf16
    float4 mv = meta[node];
    int beg = __float_as_int(mv.x), end = __float_as_int(mv.y);
    float di = mv.z;

    float acc[8] = {0.f,0.f,0.f,0.f,0.f,0.f,0.f,0.f};
#define ACC8(V) do { \
        acc[0] += bfl((V).x); acc[1] += bfh((V).x); \
        acc[2] += bfl((V).y); acc[3] += bfh((V).y); \
        acc[4] += bfl((V).z); acc[5] += bfh((V).z); \
        acc[6] += bfl((V).w); acc[7] += bfh((V).w); } while (0)

    if (g == 0) {                      // self-loop (row carries dinv[node])
        uint4 v = Xp4[(size_t)node * 8 + c];
        ACC8(v);
    }
    int e = beg + g;                   // per-lane stride-8 slot walk
    while (e < end) {
        int s0 = srcs[e];
        int e1 = e + 8;
        bool h1 = e1 < end;
        int s1 = h1 ? srcs[e1] : s0;   // dup addr when absent (L1 hit)
        uint4 v0 = Xp4[(size_t)s0 * 8 + c];
        uint4 v1 = Xp4[(size_t)s1 * 8 + c];
        ACC8(v0);
        if (h1) ACC8(v1);
        e += 16;
    }
#undef ACC8

    // fold the 8 edge-slot partials (lanes with same c, different g)
#pragma unroll
    for (int m = 8; m <= 32; m <<= 1) {
#pragma unroll
        for (int j = 0; j < 8; j++)
            acc[j] += __shfl_xor(acc[j], m, 64);
    }

    if (g == 0) {
        float4 bv0 = *(const float4*)(bias + c * 8);
        float4 bv1 = *(const float4*)(bias + c * 8 + 4);
        float r0 = fmaxf(acc[0] * di + bv0.x, 0.f);
        float r1 = fmaxf(acc[1] * di + bv0.y, 0.f);
        float r2 = fmaxf(acc[2] * di + bv0.z, 0.f);
        float r3 = fmaxf(acc[3] * di + bv0.w, 0.f);
        float r4 = fmaxf(acc[4] * di + bv1.x, 0.f);
        float r5 = fmaxf(acc[5] * di + bv1.y, 0.f);
        float r6 = fmaxf(acc[6] * di + bv1.z, 0.f);
        float r7 = fmaxf(acc[7] * di + bv1.w, 0.f);
        if (OUT16) {
            uint4 pk;
            pk.x = f2bf(r0) | (f2bf(r1) << 16);
            pk.y = f2bf(r2) | (f2bf(r3) << 16);
            pk.z = f2bf(r4) | (f2bf(r5) << 16);
            pk.w = f2bf(r6) | (f2bf(r7) << 16);
            ((uint4*)outp)[(size_t)node * 8 + c] = pk;
        } else {
            float* op = (float*)outp + (size_t)node * 64 + c * 8;
            *(float4*)(op)     = make_float4(r0, r1, r2, r3);
            *(float4*)(op + 4) = make_float4(r4, r5, r6, r7);
        }
    }
}

extern "C" void kernel_launch(void* const* d_in, const int* in_sizes, int n_in,
                              void* d_out, int out_size, void* d_ws, size_t ws_size,
                              hipStream_t stream) {
    const float* x  = (const float*)d_in[0];
    const int*   ei = (const int*)d_in[1];
    const float* W1 = (const float*)d_in[2];
    const float* b1 = (const float*)d_in[3];
    const float* W2 = (const float*)d_in[4];
    const float* b2 = (const float*)d_in[5];
    float* out = (float*)d_out;

    const int N = in_sizes[0] / 64;
    const int E = in_sizes[1] / 2;
    const int* srcA = ei;
    const int* dstA = ei + E;
    const int K = (N + NPB - 1) >> BSHIFT;   // 196

    char* ws = (char*)d_ws;
    auto alloc = [&](size_t bytes) { char* p = ws; ws += (bytes + 255) & ~(size_t)255; return p; };
    unsigned short* A16 = (unsigned short*)alloc((size_t)N * 64 * 2);  // XW' bf16 / pairs slab
    unsigned short* B16 = (unsigned short*)alloc((size_t)N * 64 * 2);  // h1 bf16
    float*  dinv  = (float*) alloc((size_t)N * 4);
    float4* meta  = (float4*)alloc((size_t)N * 16);
    int*   srcs_sorted = (int*)alloc((size_t)K * CAP * 4);             // slab layout
    int*   bcur   = (int*)  alloc(NBUCK_MAX * 4);
    unsigned int* pairs = (unsigned int*)A16;   // 8.0MB <= 12.8MB, dead before gemm

    // ---- CSR build ----
    hipMemsetAsync(bcur, 0, NBUCK_MAX * 4, stream);
    bucket_partition<<<(E + CHUNK - 1) / CHUNK, 512, 0, stream>>>(srcA, dstA, bcur, pairs, E);
    bucket_csr      <<<K, 1024, 0, stream>>>(pairs, bcur, meta, dinv, srcs_sorted, N);

    const int gemmBlocks = (N + 63) / 64;
    const int nodeBlocks = (N + 3) / 4;   // 4 waves/block x 1 node/wave

    // ---- layer 1 ----
    gemm_mfma<true>   <<<gemmBlocks, 256, 0, stream>>>(x, W1, dinv, A16, N);
    gather_nodes<true><<<nodeBlocks, 256, 0, stream>>>(A16, meta, srcs_sorted, b1, B16, N);

    // ---- layer 2 ----
    gemm_mfma<false>   <<<gemmBlocks, 256, 0, stream>>>(B16, W2, dinv, A16, N);
    gather_nodes<false><<<nodeBlocks, 256, 0, stream>>>(A16, meta, srcs_sorted, b2, out, N);
}